// Round 5
// baseline (75.404 us; speedup 1.0000x reference)
//
#include <hip/hip_runtime.h>
#include <math.h>

// ---------------------------------------------------------------------------
// VQ-VAE eval forward.  N=65536 points x K=1024 codes x D=64, fp32 in/out.
// Distances via f16x2 split-precision MFMA (16x16x32_f16), numerics as R2-R4:
//   z = zh + 2^-12 zl', e = eh + 2^-12 el'  (lo pre-scaled by 4096)
//   argmax key m = (zh.eh - esq/2) + 2^-12 (zh.el' + zl'.eh)
// R5 structure: 256 blocks x 512 thr (8 waves = 4 point-quads x 2 K-halves),
// 256 points/block (4x less codebook re-staging), 64 pts/wave (4 pt-tiles
// sharing each B read), triple-buffered 64-code chunks with COUNTED vmcnt(2)
// (2 stages in flight, no full drains), verified-conflict-free XOR swizzle.
// ---------------------------------------------------------------------------

#define QOUT_SZ  4194304            // 16*64*64*64
#define LOSS_OFF QOUT_SZ
#define IDX_OFF  (QOUT_SZ + 1)
#define PERP_OFF (QOUT_SZ + 1 + 65536)

typedef _Float16 f16x8 __attribute__((ext_vector_type(8)));
typedef _Float16 f16x4 __attribute__((ext_vector_type(4)));
typedef float    f32x4 __attribute__((ext_vector_type(4)));

// ws byte offsets
#define WS_EHI   0          // _Float16[65536] (128 KB)
#define WS_ELO   131072     // _Float16[65536] (128 KB)
#define WS_ESQ   262144     // float[1024]  (stores -0.5*||e||^2)
#define WS_HIST  266240     // float[1024]
#define WS_LOSS  270336     // float[256]

__device__ __forceinline__ void gll16(const void* g, void* l) {
    __builtin_amdgcn_global_load_lds(
        (const __attribute__((address_space(1))) void*)g,
        (__attribute__((address_space(3))) void*)l, 16, 0, 0);
}

// ---------------------------------------------------------------------------
// Prep: split-convert embedding, esq[k] = -0.5*||e_k||^2, zero hist. 64 x 256.
// ---------------------------------------------------------------------------
__global__ void vq_pre(const float* __restrict__ emb,
                       _Float16* __restrict__ ehi, _Float16* __restrict__ elo,
                       float* __restrict__ esq, float* __restrict__ hist) {
    const int t = threadIdx.x;
    const int g = blockIdx.x * 256 + t;          // float4 unit 0..16383
    float4 v = ((const float4*)emb)[g];
    float xs[4] = {v.x, v.y, v.z, v.w};
    f16x4 hi, lo;
    float ss = 0.f;
#pragma unroll
    for (int j = 0; j < 4; ++j) {
        _Float16 h = (_Float16)xs[j];
        hi[j] = h;
        lo[j] = (_Float16)((xs[j] - (float)h) * 4096.0f);
        ss = fmaf(xs[j], xs[j], ss);
    }
    ((f16x4*)ehi)[g] = hi;
    ((f16x4*)elo)[g] = lo;
    ss += __shfl_xor(ss, 1, 64);
    ss += __shfl_xor(ss, 2, 64);
    ss += __shfl_xor(ss, 4, 64);
    ss += __shfl_xor(ss, 8, 64);
    if ((t & 15) == 0) esq[g >> 4] = -0.5f * ss;
    if (blockIdx.x < 4) hist[blockIdx.x * 256 + t] = 0.f;
}

// ---------------------------------------------------------------------------
// Main. 256 blocks x 512 threads. Block owns 256 points (4 bh rows).
// Wave wv: q = wv>>1 owns points q*64..q*64+63 (4 16-pt MFMA tiles),
// ksel = wv&1 owns a 32-code half of each 64-code chunk. 16 chunks, 3-buf.
// ---------------------------------------------------------------------------
__launch_bounds__(512, 2)
__global__ void vq_main(const float* __restrict__ z,
                        const float* __restrict__ emb,
                        const _Float16* __restrict__ gehi,
                        const _Float16* __restrict__ gelo,
                        const float* __restrict__ gesq,
                        float* __restrict__ hist,
                        float* __restrict__ lossp,
                        float* __restrict__ out) {
    __shared__ __align__(16) char es[49152];      // 3 bufs x (hi 8K | lo 8K)
    __shared__ float esql[1024];                  // -esq/2

    // post-loop overlays on buf0 (all reads of es are barrier-fenced first)
    float* candv = (float*)es;                    // [256][2]
    int*   candi = (int*)(es + 2048);             // [256][2]
    int*   idxs  = (int*)(es + 4096);             // [256]
    float* redw  = (float*)(es + 5120);           // [8]

    const int tid  = threadIdx.x;
    const int blk  = blockIdx.x;                  // 0..255
    const int b    = blk >> 4;
    const int h0   = (blk & 15) << 2;             // 4 h-rows per block
    const int lane = tid & 63;
    const int wv   = tid >> 6;                    // 0..7
    const int q    = wv >> 1;                     // point quad / h row
    const int ksel = wv & 1;                      // code half of chunk
    const int col  = lane & 15;
    const int g    = lane >> 4;                   // 0..3

    // ---- stage -esq/2 into LDS ----
    esql[tid]       = gesq[tid];
    esql[tid + 512] = gesq[tid + 512];

    // ---- A fragments straight from global (lane col = point row) ----
    const float* zb = z + (size_t)b * 262144 + (size_t)h0 * 64;
    const float* zrw = zb + q * 64 + col;         // row h0+q, w = pt*16+col
    f16x8 Ah[4][2], Al[4][2];
#pragma unroll
    for (int pt = 0; pt < 4; ++pt) {
#pragma unroll
        for (int m = 0; m < 2; ++m) {
#pragma unroll
            for (int j = 0; j < 8; ++j) {
                int c = m * 32 + g * 8 + j;
                float x = zrw[pt * 16 + (size_t)c * 4096];
                _Float16 hh = (_Float16)x;
                Ah[pt][m][j] = hh;
                Al[pt][m][j] = (_Float16)((x - (float)hh) * 4096.0f);
            }
        }
    }

    // ---- staging geometry: chunk = 64 codes x 128 B per plane ----
    // LDS dest linear (wave-uniform base + lane*16); global source
    // pre-XOR-swizzled (involution), same mapping verified conflict-free (R4).
    const char* gh = (const char*)gehi;
    const char* gl = (const char*)gelo;
    const int   cc = tid >> 3;                    // staged code 0..63
    const size_t so = (size_t)cc * 128 + (size_t)(((tid & 7) ^ (cc & 7)) << 4);
    const int dofs = wv * 1024;                   // wave-uniform dest offset

#define STAGE(n, bo) do { \
        const size_t gb_ = (size_t)(n) * 8192; \
        gll16(gh + gb_ + so, es + (bo) + dofs);          \
        gll16(gl + gb_ + so, es + (bo) + 8192 + dofs);   \
    } while (0)

    // ---- per-lane B read offsets (swizzled, loop-invariant) ----
    int rb[2][2];
#pragma unroll
    for (int ct = 0; ct < 2; ++ct) {
        int cl = ksel * 32 + ct * 16 + col;
#pragma unroll
        for (int m = 0; m < 2; ++m)
            rb[ct][m] = cl * 128 + ((((m << 2) + g) ^ (cl & 7)) << 4);
    }

    float best[4][4];
    int   besti[4][4];
#pragma unroll
    for (int pt = 0; pt < 4; ++pt)
#pragma unroll
        for (int r = 0; r < 4; ++r) { best[pt][r] = -3.4e38f; besti[pt][r] = 0; }

    __syncthreads();                              // esql visible to all waves
    STAGE(0, 0);
    STAGE(1, 16384);

    // ---- k loop: 16 chunks of 64 codes, 3-buffered, counted vmcnt ----
    int cur = 0;                                  // byte offset of chunk sc's buf
    for (int sc = 0; sc < 16; ++sc) {
        if (sc < 15) asm volatile("s_waitcnt vmcnt(2)" ::: "memory");
        else         asm volatile("s_waitcnt vmcnt(0)" ::: "memory");
        __builtin_amdgcn_s_barrier();
        asm volatile("" ::: "memory");
        if (sc < 14) {                            // stage sc+2 into freed buf
            int st = cur + 32768; if (st >= 49152) st -= 49152;
            STAGE(sc + 2, st);
        }

        const char* bp = es + cur;
        const int kb = sc * 64 + ksel * 32;
#pragma unroll
        for (int ct = 0; ct < 2; ++ct) {
            const int  kcol = kb + ct * 16 + col;
            const float e2  = esql[kcol];
            f16x8 Bh0 = *(const f16x8*)(bp + rb[ct][0]);
            f16x8 Bh1 = *(const f16x8*)(bp + rb[ct][1]);
            f16x8 Bl0 = *(const f16x8*)(bp + 8192 + rb[ct][0]);
            f16x8 Bl1 = *(const f16x8*)(bp + 8192 + rb[ct][1]);
#pragma unroll
            for (int pt = 0; pt < 4; ++pt) {
                f32x4 ah = {e2, e2, e2, e2};
                f32x4 ax = {0.f, 0.f, 0.f, 0.f};
                ah = __builtin_amdgcn_mfma_f32_16x16x32_f16(Ah[pt][0], Bh0, ah, 0, 0, 0);
                ah = __builtin_amdgcn_mfma_f32_16x16x32_f16(Ah[pt][1], Bh1, ah, 0, 0, 0);
                ax = __builtin_amdgcn_mfma_f32_16x16x32_f16(Ah[pt][0], Bl0, ax, 0, 0, 0);
                ax = __builtin_amdgcn_mfma_f32_16x16x32_f16(Ah[pt][1], Bl1, ax, 0, 0, 0);
                ax = __builtin_amdgcn_mfma_f32_16x16x32_f16(Al[pt][0], Bh0, ax, 0, 0, 0);
                ax = __builtin_amdgcn_mfma_f32_16x16x32_f16(Al[pt][1], Bh1, ax, 0, 0, 0);
#pragma unroll
                for (int r = 0; r < 4; ++r) {
                    float mval = fmaf(0x1p-12f, ax[r], ah[r]);
                    if (mval > best[pt][r]) { best[pt][r] = mval; besti[pt][r] = kcol; }
                }
            }
        }
        cur += 16384; if (cur >= 49152) cur = 0;
    }
#undef STAGE

    // ---- in-wave argmin over 16 code-cols (butterfly, np tie-break) ----
#pragma unroll
    for (int mask = 1; mask <= 8; mask <<= 1) {
#pragma unroll
        for (int pt = 0; pt < 4; ++pt)
#pragma unroll
            for (int r = 0; r < 4; ++r) {
                float ov = __shfl_xor(best[pt][r], mask, 64);
                int   oi = __shfl_xor(besti[pt][r], mask, 64);
                if (ov > best[pt][r] ||
                    (ov == best[pt][r] && oi < besti[pt][r])) {
                    best[pt][r] = ov; besti[pt][r] = oi;
                }
            }
    }
    __syncthreads();                              // es reads done -> overlay OK
    if (col == 0) {
#pragma unroll
        for (int pt = 0; pt < 4; ++pt)
#pragma unroll
            for (int r = 0; r < 4; ++r) {
                int p = q * 64 + pt * 16 + g * 4 + r;
                candv[p * 2 + ksel] = best[pt][r];
                candi[p * 2 + ksel] = besti[pt][r];
            }
    }
    __syncthreads();

    // ---- combine K-halves, write idx, histogram ----
    if (tid < 256) {
        float v0 = candv[tid * 2],     v1 = candv[tid * 2 + 1];
        int   i0 = candi[tid * 2],     i1 = candi[tid * 2 + 1];
        int bi = (v1 > v0 || (v1 == v0 && i1 < i0)) ? i1 : i0;
        idxs[tid] = bi;
        atomicAdd(&hist[bi], 1.0f);               // exact int counts
        out[(size_t)IDX_OFF + (size_t)blk * 256 + tid] = (float)bi;
    }
    __syncthreads();

    // ---- epilogue: quantized write (coalesced over w) + loss partial ----
    const int w  = tid & 63;
    const int hh = (tid >> 6) & 3;                // h row within block
    const int cq = tid >> 8;                      // 0..1 -> channels cq*32..+31
    const int pl = hh * 64 + w;
    const int idx = idxs[pl];
    const float* ev = emb + (size_t)idx * 64 + cq * 32;
    const float* zr = zb + hh * 64 + w;
    float* outq = out + (size_t)b * 262144 + (size_t)(h0 + hh) * 64 + w;
    float lsum = 0.f;
#pragma unroll
    for (int i = 0; i < 8; ++i) {
        float4 qv = *(const float4*)(ev + i * 4);
        float q4[4] = {qv.x, qv.y, qv.z, qv.w};
#pragma unroll
        for (int jj = 0; jj < 4; ++jj) {
            int c = cq * 32 + i * 4 + jj;
            float zv = zr[(size_t)c * 4096];      // L3-hot re-read
            outq[(size_t)c * 4096] = q4[jj];
            float d = q4[jj] - zv;
            lsum = fmaf(d, d, lsum);
        }
    }
#pragma unroll
    for (int off = 32; off > 0; off >>= 1)
        lsum += __shfl_xor(lsum, off, 64);
    if (lane == 0) redw[wv] = lsum;
    __syncthreads();
    if (tid == 0) {
        float s = 0.f;
#pragma unroll
        for (int i = 0; i < 8; ++i) s += redw[i];
        lossp[blk] = s;
    }
}

// ---------------------------------------------------------------------------
// Finalize: loss + perplexity, fixed-order tree. 1 x 1024.
// ---------------------------------------------------------------------------
__global__ void vq_fin(const float* __restrict__ hist,
                       const float* __restrict__ lossp,
                       float* __restrict__ out) {
    __shared__ float sh[1024];
    __shared__ float sl[1024];
    int t = threadIdx.x;
    float hc = hist[t];
    float p  = hc * (1.0f / 65536.0f);
    sh[t] = p * logf(p + 1e-10f);
    sl[t] = (t < 256) ? lossp[t] : 0.f;
    __syncthreads();
    for (int s = 512; s > 0; s >>= 1) {
        if (t < s) { sh[t] += sh[t + s]; sl[t] += sl[t + s]; }
        __syncthreads();
    }
    if (t == 0) {
        out[LOSS_OFF] = 0.25f * sl[0] / (float)QOUT_SZ;
        out[PERP_OFF] = expf(-sh[0]);
    }
}

extern "C" void kernel_launch(void* const* d_in, const int* in_sizes, int n_in,
                              void* d_out, int out_size, void* d_ws, size_t ws_size,
                              hipStream_t stream) {
    const float* z   = (const float*)d_in[0];   // [16,64,64,64] fp32 NCHW
    const float* emb = (const float*)d_in[1];   // [1024,64] fp32
    float* out = (float*)d_out;
    char*  ws  = (char*)d_ws;

    _Float16* ehi   = (_Float16*)(ws + WS_EHI);
    _Float16* elo   = (_Float16*)(ws + WS_ELO);
    float*    esq   = (float*)(ws + WS_ESQ);
    float*    hist  = (float*)(ws + WS_HIST);
    float*    lossp = (float*)(ws + WS_LOSS);

    vq_pre<<<64, 256, 0, stream>>>(emb, ehi, elo, esq, hist);
    vq_main<<<256, 512, 0, stream>>>(z, emb, ehi, elo, esq, hist, lossp, out);
    vq_fin<<<1, 1024, 0, stream>>>(hist, lossp, out);
}